// Round 5
// baseline (34748.581 us; speedup 1.0000x reference)
//
#include <hip/hip_runtime.h>
#include <stdint.h>
#include <stddef.h>

typedef _Float16 f16;
typedef _Float16 half2_t __attribute__((ext_vector_type(2)));
typedef _Float16 half8_t __attribute__((ext_vector_type(8)));
typedef float   float4_t __attribute__((ext_vector_type(4)));
typedef float   float2_t __attribute__((ext_vector_type(2)));

#define T_STEPS 8192

// ---------------- workspace layout (bytes) ----------------
#define OFF_ZX   ((size_t)0)                    // Zx0 f16 [8192][4096]   = 67108864
#define OFF_HS   ((size_t)67108864)             // hs  f16 [8192][1024]   = 16777216
#define OFF_R0A  ((size_t)83886080)             // h0 ring  u64[4][8][512]   = 131072 (L2-local, XCD0)
#define OFF_R0B  (OFF_R0A + 131072)             // h0 ring  u64[8][16][512]  = 524288 (LLC, -> G1X)
#define OFF_R1A  (OFF_R0B + 524288)             // h1 ring  u64[4][8][512]   = 131072 (L2-local, XCD1)
#define OFF_ZR   (OFF_R1A + 131072)             // z1x ring u64[4][16][2048] = 1048576 (LLC, G1X->G1)
#define OFF_PG0  (OFF_ZR + 1048576)             // prog0 u32[64*32] = 8192  (G1X progress)
#define OFF_PG1  (OFF_PG0 + 8192)               // prog1 u32[32*32] = 4096  (G1 progress)
#define OFF_XC   (OFF_PG1 + 4096)               // xcd registry u32[256] = 1024
#define ZERO_BYTES ((size_t)(OFF_XC + 1024 - OFF_R0A))   // 1848320

__device__ __forceinline__ uint32_t packh(float a, float b) {
  half2_t h; h.x = (_Float16)a; h.y = (_Float16)b;
  return __builtin_bit_cast(uint32_t, h);
}
__device__ __forceinline__ float hlf(uint32_t u, int i) {
  half2_t h = __builtin_bit_cast(half2_t, u);
  return i ? (float)h.y : (float)h.x;
}
__device__ __forceinline__ float fdot2w(uint32_t w, uint32_t h, float c) {
#if __has_builtin(__builtin_amdgcn_fdot2)
  return __builtin_amdgcn_fdot2(__builtin_bit_cast(half2_t, w),
                                __builtin_bit_cast(half2_t, h), c, false);
#else
  half2_t a = __builtin_bit_cast(half2_t, w);
  half2_t b = __builtin_bit_cast(half2_t, h);
  return c + (float)a.x * (float)b.x + (float)a.y * (float)b.y;
#endif
}
__device__ __forceinline__ uint64_t ald64(const uint64_t* p) {
  return __hip_atomic_load(p, __ATOMIC_RELAXED, __HIP_MEMORY_SCOPE_AGENT);
}
__device__ __forceinline__ void ast64(uint64_t* p, uint64_t v) {
  __hip_atomic_store(p, v, __ATOMIC_RELAXED, __HIP_MEMORY_SCOPE_AGENT);
}
__device__ __forceinline__ uint32_t ald32(const uint32_t* p) {
  return __hip_atomic_load(p, __ATOMIC_RELAXED, __HIP_MEMORY_SCOPE_AGENT);
}
__device__ __forceinline__ void ast32(uint32_t* p, uint32_t v) {
  __hip_atomic_store(p, v, __ATOMIC_RELAXED, __HIP_MEMORY_SCOPE_AGENT);
}
// L1-bypassing, L2-served load (glc analog). Correct value OR stale; poll mixes
// authoritative agent loads so staleness can only cost time, never correctness.
__device__ __forceinline__ uint64_t l2ld64(const uint64_t* p) {
  uint64_t v;
  asm volatile("global_load_dwordx2 %0, %1, off sc0\n\ts_waitcnt vmcnt(0)"
               : "=v"(v) : "v"(p) : "memory");
  return v;
}
__device__ __forceinline__ uint32_t xcc_id() {
  uint32_t x;
  asm("s_getreg_b32 %0, hwreg(20, 0, 4)" : "=s"(x));  // HW_REG_XCC_ID
  return x;
}
__device__ __forceinline__ uint32_t poll_fast(const uint64_t* p, uint32_t tag) {
  int it = 0;
  for (;;) {
    uint64_t v = l2ld64(p);
    if ((uint32_t)(v >> 32) == tag) return (uint32_t)v;
    if ((++it & 7) == 7) {
      v = ald64(p);
      if ((uint32_t)(v >> 32) == tag) return (uint32_t)v;
    }
  }
}
__device__ __forceinline__ uint32_t poll_slow(const uint64_t* p, uint32_t tag) {
  int it = 0;
  for (;;) {
    uint64_t v = l2ld64(p);
    if ((uint32_t)(v >> 32) == tag) return (uint32_t)v;
    if ((++it & 7) == 7) {
      v = ald64(p);
      if ((uint32_t)(v >> 32) == tag) return (uint32_t)v;
      __builtin_amdgcn_s_sleep(1);
    }
  }
}
__device__ __forceinline__ float sigf(float x) { return 1.f / (1.f + __expf(-x)); }
__device__ __forceinline__ float tanhf_(float x) { return 2.f * sigf(2.f * x) - 1.f; }

__global__ void k_init(uint64_t* __restrict__ Z) {
  size_t n = ZERO_BYTES / 8;
  for (size_t i = blockIdx.x * blockDim.x + threadIdx.x; i < n;
       i += (size_t)gridDim.x * blockDim.x)
    Z[i] = 0ull;
}

// ---------------- generic 128x128 MFMA f16 GEMM (unchanged from R3/R4) ----------------
template <bool A16, bool OUT16>
__global__ __launch_bounds__(256) void k_gemm(const void* __restrict__ Ap,
                                              const float* __restrict__ B,
                                              const float* __restrict__ bias0,
                                              const float* __restrict__ bias1,
                                              void* __restrict__ Cp,
                                              int N, int K, int lda) {
  __shared__ __align__(16) f16 As[128 * 40];
  __shared__ __align__(16) f16 Bs[128 * 40];
  int bn = blockIdx.x * 128, bm = blockIdx.y * 128;
  int tid = threadIdx.x;
  int w = tid >> 6, l = tid & 63;
  int m0w = (w >> 1) * 64, n0w = (w & 1) * 64;
  int lr = l & 15, q = l >> 4;
  int srow = tid >> 1, skoff = (tid & 1) * 16;

  float4_t acc[4][4];
#pragma unroll
  for (int i = 0; i < 4; ++i)
#pragma unroll
    for (int j = 0; j < 4; ++j) acc[i][j] = (float4_t){0.f, 0.f, 0.f, 0.f};

  for (int kt = 0; kt < K; kt += 32) {
    __syncthreads();
    if (A16) {
      const f16* Ah = (const f16*)Ap + (size_t)(bm + srow) * lda + kt + skoff;
      uint4 u0 = *(const uint4*)Ah;
      uint4 u1 = *(const uint4*)(Ah + 8);
      *(uint4*)&As[srow * 40 + skoff] = u0;
      *(uint4*)&As[srow * 40 + skoff + 8] = u1;
    } else {
      const float* Af = (const float*)Ap + (size_t)(bm + srow) * lda + kt + skoff;
      const float4_t* A4 = (const float4_t*)Af;
      float4_t f0 = A4[0], f1 = A4[1], f2 = A4[2], f3 = A4[3];
      half8_t h0 = {(f16)f0.x, (f16)f0.y, (f16)f0.z, (f16)f0.w,
                    (f16)f1.x, (f16)f1.y, (f16)f1.z, (f16)f1.w};
      half8_t h1 = {(f16)f2.x, (f16)f2.y, (f16)f2.z, (f16)f2.w,
                    (f16)f3.x, (f16)f3.y, (f16)f3.z, (f16)f3.w};
      *(half8_t*)&As[srow * 40 + skoff] = h0;
      *(half8_t*)&As[srow * 40 + skoff + 8] = h1;
    }
    {
      const float* Bf = B + (size_t)(bn + srow) * K + kt + skoff;
      const float4_t* B4 = (const float4_t*)Bf;
      float4_t f0 = B4[0], f1 = B4[1], f2 = B4[2], f3 = B4[3];
      half8_t h0 = {(f16)f0.x, (f16)f0.y, (f16)f0.z, (f16)f0.w,
                    (f16)f1.x, (f16)f1.y, (f16)f1.z, (f16)f1.w};
      half8_t h1 = {(f16)f2.x, (f16)f2.y, (f16)f2.z, (f16)f2.w,
                    (f16)f3.x, (f16)f3.y, (f16)f3.z, (f16)f3.w};
      *(half8_t*)&Bs[srow * 40 + skoff] = h0;
      *(half8_t*)&Bs[srow * 40 + skoff + 8] = h1;
    }
    __syncthreads();
    half8_t af[4], bf[4];
#pragma unroll
    for (int i = 0; i < 4; ++i) af[i] = *(const half8_t*)&As[(m0w + 16 * i + lr) * 40 + q * 8];
#pragma unroll
    for (int j = 0; j < 4; ++j) bf[j] = *(const half8_t*)&Bs[(n0w + 16 * j + lr) * 40 + q * 8];
#pragma unroll
    for (int i = 0; i < 4; ++i)
#pragma unroll
      for (int j = 0; j < 4; ++j)
        acc[i][j] = __builtin_amdgcn_mfma_f32_16x16x32_f16(af[i], bf[j], acc[i][j], 0, 0, 0);
  }
#pragma unroll
  for (int j = 0; j < 4; ++j) {
    int n = bn + n0w + 16 * j + lr;
    float bv = bias0 ? bias0[n] : 0.f;
    if (bias1) bv += bias1[n];
#pragma unroll
    for (int i = 0; i < 4; ++i) {
#pragma unroll
      for (int r = 0; r < 4; ++r) {
        int m = bm + m0w + 16 * i + q * 4 + r;
        float v = acc[i][j][r] + bv;
        if (OUT16) ((f16*)Cp)[(size_t)m * N + n] = (f16)v;
        else       ((float*)Cp)[(size_t)m * N + n] = v;
      }
    }
  }
}

// ================= G0: layer-0 serial, 32 blocks on one XCD =================
__device__ __forceinline__ void run_l0(int r, const f16* Zx, const float* whh0,
                                       uint64_t* R0A, uint64_t* R0B,
                                       const uint32_t* prog0) {
  __shared__ uint32_t hL[512];
  __shared__ float zL[4][32];
  __shared__ uint32_t pairsL[16];
  int tid = threadIdx.x, w = tid >> 6, l = tid & 63;
  int g = w & 3, hh = w >> 2;
  int O = 32 * r;
  uint32_t wr[64];
#pragma unroll
  for (int j = 0; j < 8; ++j) {
    size_t R = (size_t)(1024 * g + O + 8 * hh + j) * 1024;
#pragma unroll
    for (int p = 0; p < 8; ++p) {
      int k = l + 64 * p;
      float2_t u = *(const float2_t*)&whh0[R + 2 * k];
      wr[j * 8 + p] = packh(u.x, u.y);
    }
  }
  float c0 = 0.f;
  bool gl = (w == 0 && l < 32);
  float zx[4] = {0, 0, 0, 0};
  if (gl)
#pragma unroll
    for (int gi = 0; gi < 4; ++gi) zx[gi] = (float)Zx[(size_t)1024 * gi + O + l];
  uint32_t pw0 = 0, pw1 = 0;
  const uint32_t* pp0 = prog0 + (2 * r) * 32;
  const uint32_t* pp1 = prog0 + (2 * r + 1) * 32;

  for (int t = 0; t < T_STEPS; ++t) {
    float zn[4] = {0, 0, 0, 0};
    if (gl && t + 1 < T_STEPS)
#pragma unroll
      for (int gi = 0; gi < 4; ++gi)
        zn[gi] = (float)Zx[(size_t)(t + 1) * 4096 + 1024 * gi + O + l];
    if (tid == 512) {  // throttle vs G1X consumption of R0B (depth 16)
      uint32_t pm = pw0 < pw1 ? pw0 : pw1;
      while (pm + 12 < (uint32_t)t) {
        pw0 = ald32(pp0); pw1 = ald32(pp1);
        pm = pw0 < pw1 ? pw0 : pw1;
      }
    }
    if (tid < 512)
      hL[tid] = poll_fast(R0A + ((size_t)((r & 3) * 8 + (t & 7)) * 512 + tid),
                          (uint32_t)t);
    __syncthreads();
    uint32_t hw[8];
#pragma unroll
    for (int p = 0; p < 8; ++p) hw[p] = hL[l + 64 * p];
    float acc[8];
#pragma unroll
    for (int j = 0; j < 8; ++j) acc[j] = 0.f;
#pragma unroll
    for (int j = 0; j < 8; ++j)
#pragma unroll
      for (int p = 0; p < 8; ++p) acc[j] = fdot2w(wr[j * 8 + p], hw[p], acc[j]);
#pragma unroll
    for (int d = 1; d < 64; d <<= 1)
#pragma unroll
      for (int j = 0; j < 8; ++j) acc[j] += __shfl_xor(acc[j], d);
    if (l < 8) zL[g][8 * hh + l] = acc[l];
    __syncthreads();
    uint32_t tg = (uint32_t)(t + 1);
    if (w == 0) {
      float h = 0.f;
      if (l < 32) {
        float zi = zL[0][l] + zx[0], zf = zL[1][l] + zx[1];
        float zg_ = zL[2][l] + zx[2], zo = zL[3][l] + zx[3];
        float ig = sigf(zi), fg = sigf(zf), gg = tanhf_(zg_), og = sigf(zo);
        c0 = fg * c0 + ig * gg;
        h = og * tanhf_(c0);
      }
      float hn = __shfl_down(h, 1);
      uint32_t pr = packh(h, hn);
      if (l < 32 && !(l & 1)) pairsL[l >> 1] = pr;
      uint32_t pj = __shfl(pr, 2 * (l & 15));
      uint64_t val = ((uint64_t)tg << 32) | pj;
      ast64(R0A + ((size_t)((l >> 4) * 8 + (tg & 7)) * 512 + 16 * r + (l & 15)), val);
    }
    __syncthreads();
    if (tid >= 64 && tid < 192) {  // 8 LLC replicas for G1X
      int s = tid - 64;
      uint64_t val = ((uint64_t)tg << 32) | pairsL[s & 15];
      ast64(R0B + ((size_t)((s >> 4) * 16 + (tg & 15)) * 512 + 16 * r + (s & 15)), val);
    }
#pragma unroll
    for (int gi = 0; gi < 4; ++gi) zx[gi] = zn[gi];
  }
}

// ================= G1: layer-1 serial, 32 blocks on one XCD =================
__device__ __forceinline__ void run_l1(int q, const float* whh1, uint64_t* R1A,
                                       const uint64_t* ZR, f16* hs,
                                       uint32_t* prog1) {
  __shared__ uint32_t hL[512];
  __shared__ float zL[4][32];
  __shared__ uint32_t zxL[64];
  int tid = threadIdx.x, w = tid >> 6, l = tid & 63;
  int g = w & 3, hh = w >> 2;
  int O = 32 * q;
  uint32_t wr[64];
#pragma unroll
  for (int j = 0; j < 8; ++j) {
    size_t R = (size_t)(1024 * g + O + 8 * hh + j) * 1024;
#pragma unroll
    for (int p = 0; p < 8; ++p) {
      int k = l + 64 * p;
      float2_t u = *(const float2_t*)&whh1[R + 2 * k];
      wr[j * 8 + p] = packh(u.x, u.y);
    }
  }
  float c1 = 0.f;

  for (int t = 0; t < T_STEPS; ++t) {
    if (tid < 512) {
      hL[tid] = poll_fast(R1A + ((size_t)((q & 3) * 8 + (t & 7)) * 512 + tid),
                          (uint32_t)t);
    } else if (tid >= 960) {  // z1x stream: 64 entries for this block
      int ii = tid - 960;
      int gg2 = ii >> 4, i = ii & 15;
      zxL[ii] = poll_slow(
          ZR + ((size_t)((q & 3) * 16 + ((t + 1) & 15)) * 2048 + 512 * gg2 + 16 * q + i),
          (uint32_t)(t + 1));
    }
    __syncthreads();
    if (tid == 512) ast32(prog1 + q * 32, (uint32_t)(t + 1));
    uint32_t hw[8];
#pragma unroll
    for (int p = 0; p < 8; ++p) hw[p] = hL[l + 64 * p];
    float acc[8];
#pragma unroll
    for (int j = 0; j < 8; ++j) acc[j] = 0.f;
#pragma unroll
    for (int j = 0; j < 8; ++j)
#pragma unroll
      for (int p = 0; p < 8; ++p) acc[j] = fdot2w(wr[j * 8 + p], hw[p], acc[j]);
#pragma unroll
    for (int d = 1; d < 64; d <<= 1)
#pragma unroll
      for (int j = 0; j < 8; ++j) acc[j] += __shfl_xor(acc[j], d);
    if (l < 8) zL[g][8 * hh + l] = acc[l];
    __syncthreads();
    uint32_t tg = (uint32_t)(t + 1);
    if (w == 0) {
      float h = 0.f;
      if (l < 32) {
        int i2 = l >> 1, hl2 = l & 1;
        float zi = zL[0][l] + hlf(zxL[i2], hl2);
        float zf = zL[1][l] + hlf(zxL[16 + i2], hl2);
        float zg_ = zL[2][l] + hlf(zxL[32 + i2], hl2);
        float zo = zL[3][l] + hlf(zxL[48 + i2], hl2);
        float ig = sigf(zi), fg = sigf(zf), gg = tanhf_(zg_), og = sigf(zo);
        c1 = fg * c1 + ig * gg;
        h = og * tanhf_(c1);
      }
      float hn = __shfl_down(h, 1);
      uint32_t pr = packh(h, hn);
      if (l < 32 && !(l & 1))
        ((uint32_t*)hs)[(size_t)t * 512 + 16 * q + (l >> 1)] = pr;
      uint32_t pj = __shfl(pr, 2 * (l & 15));
      uint64_t val = ((uint64_t)tg << 32) | pj;
      ast64(R1A + ((size_t)((l >> 4) * 8 + (tg & 7)) * 512 + 16 * q + (l & 15)), val);
    }
  }
}

// ================= G1X: w_ih1 @ h0 stream, 64 blocks (2 cohorts) =================
__device__ __forceinline__ void run_g1x(int u, const float* wih1,
                                        const float* b_ih1, const float* b_hh1,
                                        const uint64_t* R0B, uint64_t* ZR,
                                        uint32_t* prog0, const uint32_t* prog1) {
  __shared__ uint32_t hL[512];
  __shared__ uint32_t zpairs[64];
  int tid = threadIdx.x, w = tid >> 6, l = tid & 63;
  int slice = u >> 1, c = u & 1;
  int RB = 128 * slice;
  uint32_t wr[64];
  float bb[8];
#pragma unroll
  for (int j = 0; j < 8; ++j) {
    int row = RB + 8 * w + j;
    bb[j] = b_ih1[row] + b_hh1[row];
    size_t R = (size_t)row * 1024;
#pragma unroll
    for (int p = 0; p < 8; ++p) {
      int k = l + 64 * p;
      float2_t uu = *(const float2_t*)&wih1[R + 2 * k];
      wr[j * 8 + p] = packh(uu.x, uu.y);
    }
  }
  uint32_t pz = 0;
  const uint32_t* pp = prog1 + (u & 31) * 32;
  for (int t = c; t < T_STEPS; t += 2) {
    if (tid == 520) {  // throttle vs G1 consumption of ZR (depth 16)
      while (pz + 8 < (uint32_t)t) pz = ald32(pp);
    }
    if (tid < 512)
      hL[tid] = poll_slow(
          R0B + ((size_t)((u & 7) * 16 + ((t + 1) & 15)) * 512 + tid),
          (uint32_t)(t + 1));
    __syncthreads();
    if (tid == 512) ast32(prog0 + u * 32, (uint32_t)(t + 1));
    uint32_t hw[8];
#pragma unroll
    for (int p = 0; p < 8; ++p) hw[p] = hL[l + 64 * p];
    float acc[8];
#pragma unroll
    for (int j = 0; j < 8; ++j) acc[j] = 0.f;
#pragma unroll
    for (int j = 0; j < 8; ++j)
#pragma unroll
      for (int p = 0; p < 8; ++p) acc[j] = fdot2w(wr[j * 8 + p], hw[p], acc[j]);
#pragma unroll
    for (int d = 1; d < 64; d <<= 1)
#pragma unroll
      for (int j = 0; j < 8; ++j) acc[j] += __shfl_xor(acc[j], d);
    if (l < 4)
      zpairs[4 * w + l] = packh(acc[2 * l] + bb[2 * l], acc[2 * l + 1] + bb[2 * l + 1]);
    __syncthreads();
    if (tid < 256) {
      uint64_t val = ((uint64_t)(uint32_t)(t + 1) << 32) | zpairs[tid & 63];
      ast64(ZR + ((size_t)((tid >> 6) * 16 + ((t + 1) & 15)) * 2048 + 64 * slice + (tid & 63)),
            val);
    }
  }
}

__global__ __launch_bounds__(1024, 4) void k_serial(
    const f16* __restrict__ Zx, const float* __restrict__ whh0,
    const float* __restrict__ wih1, const float* __restrict__ whh1,
    const float* __restrict__ b_ih1, const float* __restrict__ b_hh1,
    f16* __restrict__ hs, uint64_t* __restrict__ R0A, uint64_t* __restrict__ R0B,
    uint64_t* __restrict__ R1A, uint64_t* __restrict__ ZR,
    uint32_t* __restrict__ prog0, uint32_t* __restrict__ prog1,
    uint32_t* __restrict__ xc) {
  __shared__ int srole[2];
  if (threadIdx.x == 0) {
    uint32_t xcd = xcc_id() & 7u;
    uint32_t rk = atomicAdd(&xc[xcd * 16], 1u);
    atomicOr(&xc[128], 1u << xcd);
    atomicAdd(&xc[129], 1u);
    while (ald32(&xc[129]) < (uint32_t)gridDim.x) __builtin_amdgcn_s_sleep(8);
    uint32_t mask = ald32(&xc[128]);
    srole[0] = __popc(mask & ((1u << xcd) - 1u));  // dense xcd index
    srole[1] = (int)rk;
  }
  __syncthreads();
  int dense = srole[0], rk = srole[1];
  if (rk >= 32) return;
  if (dense == 0)      run_l0(rk, Zx, whh0, R0A, R0B, prog0);
  else if (dense == 1) run_l1(rk, whh1, R1A, ZR, hs, prog1);
  else if (dense == 2 || dense == 3)
    run_g1x((dense - 2) * 32 + rk, wih1, b_ih1, b_hh1, R0B, ZR, prog0, prog1);
}

// ---------------- value head ----------------
__global__ void k_values(const f16* __restrict__ hs, const float* __restrict__ w_val,
                         const float* __restrict__ b_val, float* __restrict__ outv) {
  int t = blockIdx.x * 4 + (threadIdx.x >> 6);
  int l = threadIdx.x & 63;
  const f16* row = hs + (size_t)t * 1024 + l * 16;
  const float* wv = w_val + l * 16;
  float s = 0.f;
#pragma unroll
  for (int i = 0; i < 16; ++i) s += (float)row[i] * wv[i];
#pragma unroll
  for (int d = 1; d < 64; d <<= 1) s += __shfl_xor(s, d);
  if (l == 0) outv[t] = s + b_val[0];
}

// ---------------- softmax ----------------
__global__ void k_softmax(float* __restrict__ out) {
  int t = blockIdx.x * 4 + (threadIdx.x >> 6);
  int l = threadIdx.x & 63;
  float* row = out + (size_t)t * 512;
  float v[8];
  float m = -1e30f;
#pragma unroll
  for (int i = 0; i < 8; ++i) { v[i] = row[l + 64 * i]; m = fmaxf(m, v[i]); }
#pragma unroll
  for (int d = 1; d < 64; d <<= 1) m = fmaxf(m, __shfl_xor(m, d));
  float s = 0.f;
#pragma unroll
  for (int i = 0; i < 8; ++i) { v[i] = __expf(v[i] - m); s += v[i]; }
#pragma unroll
  for (int d = 1; d < 64; d <<= 1) s += __shfl_xor(s, d);
  float inv = 1.f / s;
#pragma unroll
  for (int i = 0; i < 8; ++i) row[l + 64 * i] = v[i] * inv;
}

extern "C" void kernel_launch(void* const* d_in, const int* in_sizes, int n_in,
                              void* d_out, int out_size, void* d_ws, size_t ws_size,
                              hipStream_t stream) {
  const float* x      = (const float*)d_in[0];
  const float* w_ih0  = (const float*)d_in[1];
  const float* w_hh0  = (const float*)d_in[2];
  const float* b_ih0  = (const float*)d_in[3];
  const float* b_hh0  = (const float*)d_in[4];
  const float* w_ih1  = (const float*)d_in[5];
  const float* w_hh1  = (const float*)d_in[6];
  const float* b_ih1  = (const float*)d_in[7];
  const float* b_hh1  = (const float*)d_in[8];
  const float* w_pol  = (const float*)d_in[9];
  const float* b_pol  = (const float*)d_in[10];
  const float* w_val  = (const float*)d_in[11];
  const float* b_val  = (const float*)d_in[12];

  char* ws = (char*)d_ws;
  f16*      Zx   = (f16*)(ws + OFF_ZX);
  f16*      hs   = (f16*)(ws + OFF_HS);
  uint64_t* R0A  = (uint64_t*)(ws + OFF_R0A);
  uint64_t* R0B  = (uint64_t*)(ws + OFF_R0B);
  uint64_t* R1A  = (uint64_t*)(ws + OFF_R1A);
  uint64_t* ZR   = (uint64_t*)(ws + OFF_ZR);
  uint32_t* PG0  = (uint32_t*)(ws + OFF_PG0);
  uint32_t* PG1  = (uint32_t*)(ws + OFF_PG1);
  uint32_t* XC   = (uint32_t*)(ws + OFF_XC);
  float*    out  = (float*)d_out;

  k_init<<<256, 256, 0, stream>>>((uint64_t*)(ws + OFF_R0A));
  k_gemm<false, true><<<dim3(32, 64), 256, 0, stream>>>(
      (const void*)x, w_ih0, b_ih0, b_hh0, (void*)Zx, 4096, 512, 512);
  k_serial<<<256, 1024, 0, stream>>>(Zx, w_hh0, w_ih1, w_hh1, b_ih1, b_hh1, hs,
                                     R0A, R0B, R1A, ZR, PG0, PG1, XC);
  k_gemm<true, false><<<dim3(4, 64), 256, 0, stream>>>(
      (const void*)hs, w_pol, b_pol, nullptr, (void*)out, 512, 1024, 1024);
  k_values<<<2048, 256, 0, stream>>>(hs, w_val, b_val, out + (size_t)8192 * 512);
  k_softmax<<<2048, 256, 0, stream>>>(out);
}